// Round 1
// baseline (765.190 us; speedup 1.0000x reference)
//
#include <hip/hip_runtime.h>
#include <math.h>

#define H 2048
#define S 4096
#define B 16
#define POOL 4096
#define EPS 1e-6f
#define INV_SQRT_H 0.022097086912079608f   // 1/sqrt(2048)

// Workspace layout (floats):
#define OFF_Q     0          // [0, 2048)        q = Wq @ lq
#define OFF_QK    2048       // [2048, 4096)     qk = Wk^T @ q  (atomic, zeroed)
#define OFF_SSQ   4096       // [4096, 4112)     B sum-of-squares (atomic, zeroed)
#define OFF_DEN   4112       // [4112, 4128)     B softmax denominators (written by k_red)
#define OFF_NUM   4128       // [4128, 36896)    B*H weighted sums (written by k_red)
#define OFF_PV    36896      // [36896, 69664)   B*H pooled * norm_w
#define OFF_PART  69664      // npart partials: B*npart*H floats, then dpart B*npart

typedef float f4 __attribute__((ext_vector_type(4)));

__device__ __forceinline__ float wave_reduce(float v) {
#pragma unroll
  for (int off = 32; off > 0; off >>= 1) v += __shfl_xor(v, off, 64);
  return v;
}

// q[d] = sum_h lq[h] * Wq[d*H + h]   (one wave per d); also zeroes qk+ssq scratch.
__global__ __launch_bounds__(256) void k_q(const float* __restrict__ Wq,
                                           const float* __restrict__ lq,
                                           float* __restrict__ ws) {
  // zero qk (2048) + ssq (16) = 2064 floats, contiguous at OFF_QK
  {
    int i = blockIdx.x * 256 + threadIdx.x;
    if (blockIdx.x < 9 && i < 2064) ws[OFF_QK + i] = 0.f;
  }
  const int d = blockIdx.x * 4 + (threadIdx.x >> 6);
  const int lane = threadIdx.x & 63;
  const float4* row = (const float4*)(Wq + (size_t)d * H);
  const float4* l4  = (const float4*)lq;
  float acc = 0.f;
#pragma unroll
  for (int k = 0; k < H / 4 / 64; ++k) {
    float4 w = row[lane + k * 64];
    float4 x = l4[lane + k * 64];
    acc += w.x * x.x + w.y * x.y + w.z * x.z + w.w * x.w;
  }
  acc = wave_reduce(acc);
  if (lane == 0) ws[OFF_Q + d] = acc;
}

// qk[h] += sum_{d in chunk} q[d] * Wk[d*H + h];  grid (H/256, 32)
__global__ __launch_bounds__(256) void k_qk(const float* __restrict__ Wk,
                                            const float* __restrict__ ws_q,
                                            float* __restrict__ qk) {
  const int h  = blockIdx.x * 256 + threadIdx.x;
  const int d0 = blockIdx.y * 64;
  float local = 0.f;
#pragma unroll 8
  for (int dd = 0; dd < 64; ++dd) {
    local += ws_q[d0 + dd] * Wk[(size_t)(d0 + dd) * H + h];
  }
  atomicAdd(&qk[h], local);
}

// Streaming pass over X. grid (npart, B), 256 threads (4 waves).
// Wave w owns rows [bx*rows_pb + w*rpw, +rpw); lane l owns cols 4*(l+64k).
// Mask bits preloaded into a 64-bit register (no dependent per-row load).
// NO global atomics: block writes its partial sum; k_red reduces.
__global__ __launch_bounds__(256, 4) void k_main(const float* __restrict__ X,
                                                 const int* __restrict__ mask,
                                                 const float* __restrict__ qk,
                                                 float* __restrict__ part,
                                                 float* __restrict__ dpart,
                                                 int npart) {
  const int b  = blockIdx.y;
  const int bx = blockIdx.x;
  const int rows_pb = S / npart;       // rows per block
  const int rpw = rows_pb >> 2;        // rows per wave (<= 64)
  const int t = threadIdx.x;
  const int lane = t & 63;
  const int wv   = t >> 6;

  __shared__ float lnum[H];
  __shared__ float lden;
#pragma unroll
  for (int j = 0; j < 8; ++j) lnum[t * 8 + j] = 0.f;
  if (t == 0) lden = 0.f;

  const f4* qk4 = (const f4*)qk;
  f4 qv[8];
#pragma unroll
  for (int k = 0; k < 8; ++k) qv[k] = qk4[lane + 64 * k];

  f4 acc[8];
#pragma unroll
  for (int k = 0; k < 8; ++k) acc[k] = (f4)(0.f);
  float denl = 0.f;

  const int srow0 = bx * rows_pb + wv * rpw;
  const float* Xw = X + (size_t)b * S * H + (size_t)srow0 * H;
  const int*   mb = mask + b * S + srow0;

  // preload all this wave's mask values into one 64-bit register
  unsigned long long bits = __ballot(lane < rpw ? (mb[lane] != 0) : 0);

  __syncthreads();  // lnum zeroing visible before LDS atomics

  for (int r = 0; r < rpw; ++r) {
    if (!((bits >> r) & 1ull)) continue;   // register bit-test, wave-uniform
    const f4* xp = (const f4*)(Xw + (size_t)r * H);
    f4 x[8];
#pragma unroll
    for (int k = 0; k < 8; ++k) x[k] = __builtin_nontemporal_load(&xp[lane + 64 * k]);
    float p = 0.f;
#pragma unroll
    for (int k = 0; k < 8; ++k)
      p += x[k].x * qv[k].x + x[k].y * qv[k].y + x[k].z * qv[k].z + x[k].w * qv[k].w;
    p = wave_reduce(p);
    float w = __expf(p * INV_SQRT_H);
    denl += w;
#pragma unroll
    for (int k = 0; k < 8; ++k) acc[k] += w * x[k];
  }

  // block combine in LDS (max 4-way contention), then plain coalesced store
#pragma unroll
  for (int k = 0; k < 8; ++k) {
    const int c = 4 * (lane + 64 * k);
    atomicAdd(&lnum[c + 0], acc[k].x);
    atomicAdd(&lnum[c + 1], acc[k].y);
    atomicAdd(&lnum[c + 2], acc[k].z);
    atomicAdd(&lnum[c + 3], acc[k].w);
  }
  if (lane == 0) atomicAdd(&lden, denl);
  __syncthreads();

  f4* pb = (f4*)(part + ((size_t)b * npart + bx) * H);
  const f4* ln4 = (const f4*)lnum;
  pb[t * 2]     = ln4[t * 2];
  pb[t * 2 + 1] = ln4[t * 2 + 1];
  if (t == 0) dpart[b * npart + bx] = lden;
}

// num[b,h] = sum_j part[(b*npart+j)*H + h]; den[b] = sum_j dpart[b*npart+j]
__global__ __launch_bounds__(256) void k_red(const float* __restrict__ part,
                                             const float* __restrict__ dpart,
                                             float* __restrict__ num,
                                             float* __restrict__ den,
                                             int npart) {
  const int idx = blockIdx.x * 256 + threadIdx.x;   // 0 .. B*H-1
  const int b = idx >> 11;
  const int h = idx & (H - 1);
  float s = 0.f;
  for (int j = 0; j < npart; ++j) s += part[((size_t)b * npart + j) * H + h];
  num[idx] = s;
  if (idx < B) {
    float d = 0.f;
    for (int j = 0; j < npart; ++j) d += dpart[idx * npart + j];
    den[idx] = d;
  }
}

// pv[b,d] = nw[d] * (num[b]·Wv_row_d)/den[b]; also accumulate ssq[b] partials.
__global__ __launch_bounds__(256) void k_pv(const float* __restrict__ Wv,
                                            const float* __restrict__ num,
                                            const float* __restrict__ den,
                                            const float* __restrict__ nw,
                                            float* __restrict__ pv,
                                            float* __restrict__ ssq) {
  const int d = blockIdx.x * 4 + (threadIdx.x >> 6);
  const int lane = threadIdx.x & 63;
  const int wv   = threadIdx.x >> 6;
  const float4* wrow = (const float4*)(Wv + (size_t)d * H);
  const float4* n4   = (const float4*)num;
  float acc[B];
#pragma unroll
  for (int bb = 0; bb < B; ++bb) acc[bb] = 0.f;
  for (int k = lane; k < H / 4; k += 64) {
    float4 w = wrow[k];
#pragma unroll
    for (int bb = 0; bb < B; ++bb) {
      float4 v = n4[bb * (H / 4) + k];
      acc[bb] += w.x * v.x + w.y * v.y + w.z * v.z + w.w * v.w;
    }
  }
#pragma unroll
  for (int bb = 0; bb < B; ++bb) acc[bb] = wave_reduce(acc[bb]);

  __shared__ float sblk[4][B];
  if (lane == 0) {
    const float nwd = nw[d];
#pragma unroll
    for (int bb = 0; bb < B; ++bb) {
      float p = acc[bb] / den[bb];
      pv[bb * H + d] = p * nwd;
      sblk[wv][bb] = p * p;
    }
  }
  __syncthreads();
  if (threadIdx.x < B) {
    atomicAdd(&ssq[threadIdx.x],
              sblk[0][threadIdx.x] + sblk[1][threadIdx.x] +
              sblk[2][threadIdx.x] + sblk[3][threadIdx.x]);
  }
}

// out[b,p] = rsqrt(ssq[b]/H+eps) * sum_d pv[b,d] * Wo[p*H+d]
__global__ __launch_bounds__(256) void k_out(const float* __restrict__ Wo,
                                             const float* __restrict__ pv,
                                             const float* __restrict__ ssq,
                                             float* __restrict__ out) {
  const int p = blockIdx.x * 4 + (threadIdx.x >> 6);
  const int lane = threadIdx.x & 63;
  const float4* wrow = (const float4*)(Wo + (size_t)p * H);
  const float4* n4   = (const float4*)pv;
  float acc[B];
#pragma unroll
  for (int bb = 0; bb < B; ++bb) acc[bb] = 0.f;
  for (int k = lane; k < H / 4; k += 64) {
    float4 w = wrow[k];
#pragma unroll
    for (int bb = 0; bb < B; ++bb) {
      float4 v = n4[bb * (H / 4) + k];
      acc[bb] += w.x * v.x + w.y * v.y + w.z * v.z + w.w * v.w;
    }
  }
#pragma unroll
  for (int bb = 0; bb < B; ++bb) acc[bb] = wave_reduce(acc[bb]);
  if (lane == 0) {
#pragma unroll
    for (int bb = 0; bb < B; ++bb) {
      float sc = rsqrtf(ssq[bb] * (1.0f / (float)H) + EPS);
      out[bb * POOL + p] = acc[bb] * sc;
    }
  }
}

extern "C" void kernel_launch(void* const* d_in, const int* in_sizes, int n_in,
                              void* d_out, int out_size, void* d_ws, size_t ws_size,
                              hipStream_t stream) {
  (void)in_sizes; (void)n_in; (void)out_size;
  const float* X    = (const float*)d_in[0];
  const int*   mask = (const int*)d_in[1];
  const float* lq   = (const float*)d_in[2];
  const float* Wq   = (const float*)d_in[3];
  const float* Wk   = (const float*)d_in[4];
  const float* Wv   = (const float*)d_in[5];
  const float* Wo   = (const float*)d_in[6];
  const float* nw   = (const float*)d_in[7];
  float* out = (float*)d_out;
  float* ws  = (float*)d_ws;

  // pick npart by available workspace (needs OFF_PART + B*npart*H + B*npart floats)
  int npart = 64;
  while (npart > 16 &&
         ws_size < ((size_t)OFF_PART + (size_t)B * npart * H + (size_t)B * npart) * sizeof(float))
    npart >>= 1;

  float* part  = ws + OFF_PART;
  float* dpart = part + (size_t)B * npart * H;

  k_q   <<<H / 4, 256, 0, stream>>>(Wq, lq, ws);
  k_qk  <<<dim3(H / 256, 32), 256, 0, stream>>>(Wk, ws + OFF_Q, ws + OFF_QK);
  k_main<<<dim3(npart, B), 256, 0, stream>>>(X, mask, ws + OFF_QK, part, dpart, npart);
  k_red <<<(B * H) / 256, 256, 0, stream>>>(part, dpart, ws + OFF_NUM, ws + OFF_DEN, npart);
  k_pv  <<<H / 4, 256, 0, stream>>>(Wv, ws + OFF_NUM, ws + OFF_DEN, nw,
                                    ws + OFF_PV, ws + OFF_SSQ);
  k_out <<<POOL / 4, 256, 0, stream>>>(Wo, ws + OFF_PV, ws + OFF_SSQ, out);
}

// Round 2
// 763.093 us; speedup vs baseline: 1.0027x; 1.0027x over previous
//
#include <hip/hip_runtime.h>
#include <math.h>

#define H 2048
#define S 4096
#define B 16
#define POOL 4096
#define EPS 1e-6f
#define INV_SQRT_H 0.022097086912079608f   // 1/sqrt(2048)

// Workspace layout (floats):
#define OFF_Q     0          // [0, 2048)        q = Wq @ lq
#define OFF_QK    2048       // [2048, 4096)     qk = Wk^T @ q  (atomic, zeroed)
#define OFF_SSQ   4096       // [4096, 4112)     B sum-of-squares (atomic, zeroed)
#define OFF_DEN   4112       // [4112, 4128)     B softmax denominators (written by k_red)
#define OFF_NUM   4128       // [4128, 36896)    B*H weighted sums (written by k_red)
#define OFF_PV    36896      // [36896, 69664)   B*H pooled * norm_w
#define OFF_PART  69664      // npart partials: B*npart*H floats, then dpart B*npart

typedef float f4 __attribute__((ext_vector_type(4)));

__device__ __forceinline__ float wave_reduce(float v) {
#pragma unroll
  for (int off = 32; off > 0; off >>= 1) v += __shfl_xor(v, off, 64);
  return v;
}

// q[d] = sum_h lq[h] * Wq[d*H + h]   (one wave per d); also zeroes qk+ssq scratch.
__global__ __launch_bounds__(256) void k_q(const float* __restrict__ Wq,
                                           const float* __restrict__ lq,
                                           float* __restrict__ ws) {
  // zero qk (2048) + ssq (16) = 2064 floats, contiguous at OFF_QK
  {
    int i = blockIdx.x * 256 + threadIdx.x;
    if (blockIdx.x < 9 && i < 2064) ws[OFF_QK + i] = 0.f;
  }
  const int d = blockIdx.x * 4 + (threadIdx.x >> 6);
  const int lane = threadIdx.x & 63;
  const float4* row = (const float4*)(Wq + (size_t)d * H);
  const float4* l4  = (const float4*)lq;
  float acc = 0.f;
#pragma unroll
  for (int k = 0; k < H / 4 / 64; ++k) {
    float4 w = row[lane + k * 64];
    float4 x = l4[lane + k * 64];
    acc += w.x * x.x + w.y * x.y + w.z * x.z + w.w * x.w;
  }
  acc = wave_reduce(acc);
  if (lane == 0) ws[OFF_Q + d] = acc;
}

// qk[h] += sum_{d in chunk} q[d] * Wk[d*H + h];  grid (H/256, 32)
__global__ __launch_bounds__(256) void k_qk(const float* __restrict__ Wk,
                                            const float* __restrict__ ws_q,
                                            float* __restrict__ qk) {
  const int h  = blockIdx.x * 256 + threadIdx.x;
  const int d0 = blockIdx.y * 64;
  float local = 0.f;
#pragma unroll 8
  for (int dd = 0; dd < 64; ++dd) {
    local += ws_q[d0 + dd] * Wk[(size_t)(d0 + dd) * H + h];
  }
  atomicAdd(&qk[h], local);
}

// Streaming pass over X. grid (npart, B), 256 threads (4 waves).
// qk staged in LDS (frees 32 VGPRs -> no spill at the 128-VGPR/4-block cap).
// Mask bits preloaded into a 64-bit register (no dependent per-row load).
// NO global atomics: block writes its partial sum; k_red reduces.
__global__ __launch_bounds__(256, 4) void k_main(const float* __restrict__ X,
                                                 const int* __restrict__ mask,
                                                 const float* __restrict__ qk,
                                                 float* __restrict__ part,
                                                 float* __restrict__ dpart,
                                                 int npart) {
  const int b  = blockIdx.y;
  const int bx = blockIdx.x;
  const int rows_pb = S / npart;       // rows per block
  const int rpw = rows_pb >> 2;        // rows per wave (<= 64)
  const int t = threadIdx.x;
  const int lane = t & 63;
  const int wv   = t >> 6;

  __shared__ f4 qs[H / 4];             // 8 KB: query vector, read every row
  __shared__ float lnum[H];            // 8 KB: block-level combine buffer
  __shared__ float lden;

  const f4* qk4 = (const f4*)qk;
  qs[t * 2]     = qk4[t * 2];
  qs[t * 2 + 1] = qk4[t * 2 + 1];
#pragma unroll
  for (int j = 0; j < 8; ++j) lnum[t * 8 + j] = 0.f;
  if (t == 0) lden = 0.f;

  f4 acc[8];
#pragma unroll
  for (int k = 0; k < 8; ++k) acc[k] = (f4)(0.f);
  float denl = 0.f;

  const int srow0 = bx * rows_pb + wv * rpw;
  const float* Xw = X + (size_t)b * S * H + (size_t)srow0 * H;
  const int*   mb = mask + b * S + srow0;

  // preload all this wave's mask values into one 64-bit register
  unsigned long long bits = __ballot(lane < rpw ? (mb[lane] != 0) : 0);

  __syncthreads();  // qs filled + lnum zeroed before use

  for (int r = 0; r < rpw; ++r) {
    if (!((bits >> r) & 1ull)) continue;   // register bit-test, wave-uniform
    const f4* xp = (const f4*)(Xw + (size_t)r * H);
    f4 x[8];
#pragma unroll
    for (int k = 0; k < 8; ++k) x[k] = __builtin_nontemporal_load(&xp[lane + 64 * k]);
    float p = 0.f;
#pragma unroll
    for (int k = 0; k < 8; ++k) {
      f4 q = qs[lane + 64 * k];
      p += x[k].x * q.x + x[k].y * q.y + x[k].z * q.z + x[k].w * q.w;
    }
    p = wave_reduce(p);
    float w = __expf(p * INV_SQRT_H);
    denl += w;
#pragma unroll
    for (int k = 0; k < 8; ++k) acc[k] += w * x[k];
  }

  // block combine in LDS (max 4-way contention), then plain coalesced store
#pragma unroll
  for (int k = 0; k < 8; ++k) {
    const int c = 4 * (lane + 64 * k);
    atomicAdd(&lnum[c + 0], acc[k].x);
    atomicAdd(&lnum[c + 1], acc[k].y);
    atomicAdd(&lnum[c + 2], acc[k].z);
    atomicAdd(&lnum[c + 3], acc[k].w);
  }
  if (lane == 0) atomicAdd(&lden, denl);
  __syncthreads();

  f4* pb = (f4*)(part + ((size_t)b * npart + bx) * H);
  const f4* ln4 = (const f4*)lnum;
  pb[t * 2]     = ln4[t * 2];
  pb[t * 2 + 1] = ln4[t * 2 + 1];
  if (t == 0) dpart[b * npart + bx] = lden;
}

// num[b,h] = sum_j part[(b*npart+j)*H + h]; den[b] = sum_j dpart[b*npart+j]
__global__ __launch_bounds__(256) void k_red(const float* __restrict__ part,
                                             const float* __restrict__ dpart,
                                             float* __restrict__ num,
                                             float* __restrict__ den,
                                             int npart) {
  const int idx = blockIdx.x * 256 + threadIdx.x;   // 0 .. B*H-1
  const int b = idx >> 11;
  const int h = idx & (H - 1);
  float s = 0.f;
  for (int j = 0; j < npart; ++j) s += part[((size_t)b * npart + j) * H + h];
  num[idx] = s;
  if (idx < B) {
    float d = 0.f;
    for (int j = 0; j < npart; ++j) d += dpart[idx * npart + j];
    den[idx] = d;
  }
}

// pv[b,d] = nw[d] * (num[b]·Wv_row_d)/den[b]; also accumulate ssq[b] partials.
__global__ __launch_bounds__(256) void k_pv(const float* __restrict__ Wv,
                                            const float* __restrict__ num,
                                            const float* __restrict__ den,
                                            const float* __restrict__ nw,
                                            float* __restrict__ pv,
                                            float* __restrict__ ssq) {
  const int d = blockIdx.x * 4 + (threadIdx.x >> 6);
  const int lane = threadIdx.x & 63;
  const int wv   = threadIdx.x >> 6;
  const float4* wrow = (const float4*)(Wv + (size_t)d * H);
  const float4* n4   = (const float4*)num;
  float acc[B];
#pragma unroll
  for (int bb = 0; bb < B; ++bb) acc[bb] = 0.f;
  for (int k = lane; k < H / 4; k += 64) {
    float4 w = wrow[k];
#pragma unroll
    for (int bb = 0; bb < B; ++bb) {
      float4 v = n4[bb * (H / 4) + k];
      acc[bb] += w.x * v.x + w.y * v.y + w.z * v.z + w.w * v.w;
    }
  }
#pragma unroll
  for (int bb = 0; bb < B; ++bb) acc[bb] = wave_reduce(acc[bb]);

  __shared__ float sblk[4][B];
  if (lane == 0) {
    const float nwd = nw[d];
#pragma unroll
    for (int bb = 0; bb < B; ++bb) {
      float p = acc[bb] / den[bb];
      pv[bb * H + d] = p * nwd;
      sblk[wv][bb] = p * p;
    }
  }
  __syncthreads();
  if (threadIdx.x < B) {
    atomicAdd(&ssq[threadIdx.x],
              sblk[0][threadIdx.x] + sblk[1][threadIdx.x] +
              sblk[2][threadIdx.x] + sblk[3][threadIdx.x]);
  }
}

// out[b,p] = rsqrt(ssq[b]/H+eps) * sum_d pv[b,d] * Wo[p*H+d]
__global__ __launch_bounds__(256) void k_out(const float* __restrict__ Wo,
                                             const float* __restrict__ pv,
                                             const float* __restrict__ ssq,
                                             float* __restrict__ out) {
  const int p = blockIdx.x * 4 + (threadIdx.x >> 6);
  const int lane = threadIdx.x & 63;
  const float4* wrow = (const float4*)(Wo + (size_t)p * H);
  const float4* n4   = (const float4*)pv;
  float acc[B];
#pragma unroll
  for (int bb = 0; bb < B; ++bb) acc[bb] = 0.f;
  for (int k = lane; k < H / 4; k += 64) {
    float4 w = wrow[k];
#pragma unroll
    for (int bb = 0; bb < B; ++bb) {
      float4 v = n4[bb * (H / 4) + k];
      acc[bb] += w.x * v.x + w.y * v.y + w.z * v.z + w.w * v.w;
    }
  }
#pragma unroll
  for (int bb = 0; bb < B; ++bb) acc[bb] = wave_reduce(acc[bb]);
  if (lane == 0) {
#pragma unroll
    for (int bb = 0; bb < B; ++bb) {
      float sc = rsqrtf(ssq[bb] * (1.0f / (float)H) + EPS);
      out[bb * POOL + p] = acc[bb] * sc;
    }
  }
}

extern "C" void kernel_launch(void* const* d_in, const int* in_sizes, int n_in,
                              void* d_out, int out_size, void* d_ws, size_t ws_size,
                              hipStream_t stream) {
  (void)in_sizes; (void)n_in; (void)out_size;
  const float* X    = (const float*)d_in[0];
  const int*   mask = (const int*)d_in[1];
  const float* lq   = (const float*)d_in[2];
  const float* Wq   = (const float*)d_in[3];
  const float* Wk   = (const float*)d_in[4];
  const float* Wv   = (const float*)d_in[5];
  const float* Wo   = (const float*)d_in[6];
  const float* nw   = (const float*)d_in[7];
  float* out = (float*)d_out;
  float* ws  = (float*)d_ws;

  // pick npart by available workspace (needs OFF_PART + B*npart*H + B*npart floats)
  int npart = 64;
  while (npart > 16 &&
         ws_size < ((size_t)OFF_PART + (size_t)B * npart * H + (size_t)B * npart) * sizeof(float))
    npart >>= 1;

  float* part  = ws + OFF_PART;
  float* dpart = part + (size_t)B * npart * H;

  k_q   <<<H / 4, 256, 0, stream>>>(Wq, lq, ws);
  k_qk  <<<dim3(H / 256, 32), 256, 0, stream>>>(Wk, ws + OFF_Q, ws + OFF_QK);
  k_main<<<dim3(npart, B), 256, 0, stream>>>(X, mask, ws + OFF_QK, part, dpart, npart);
  k_red <<<(B * H) / 256, 256, 0, stream>>>(part, dpart, ws + OFF_NUM, ws + OFF_DEN, npart);
  k_pv  <<<H / 4, 256, 0, stream>>>(Wv, ws + OFF_NUM, ws + OFF_DEN, nw,
                                    ws + OFF_PV, ws + OFF_SSQ);
  k_out <<<POOL / 4, 256, 0, stream>>>(Wo, ws + OFF_PV, ws + OFF_SSQ, out);
}